// Round 5
// baseline (267.779 us; speedup 1.0000x reference)
//
#include <hip/hip_runtime.h>

#define BSZ  8192
#define DDIM 256
#define BM 128
#define BN 128
#define NT   64                  // tiles per dimension
#define NTRI (NT * (NT + 1) / 2) // 2080 upper-triangle tiles

typedef float f32x4 __attribute__((ext_vector_type(4)));
typedef short bf16x8 __attribute__((ext_vector_type(8)));

__device__ __forceinline__ unsigned short f32_to_bf16(float f) {
    unsigned int u = __float_as_uint(f);
    u += 0x7fffu + ((u >> 16) & 1u);   // RNE
    return (unsigned short)(u >> 16);
}

// epilogue constants
#define K_E1   20.60992915555662f    // (1/T)*log2(e)
#define K_E2  -20.60992915555662f
#define K_INVT 14.285714285714286f   // 1/T
#define K_N1   1.4285714285714286f   // 1/(1-0.3)
#define K_N2   0.5714285714285714f   // 0.4/0.7

// ---------------- L2-normalize rows; emit MFMA-fragment-native layout ----------------
// anchorT: tile (C = k/32, R = row/16) at ((C*512 + R) * 512) shorts; within-tile
// lane l = (row%16) + 16*((k%32)/8) holds elems j=0..7 (k = C*32 + (l>>4)*8 + j).
__global__ __launch_bounds__(256) void norm_kernel(const float* __restrict__ feat,
                                                   unsigned short* __restrict__ anchorT) {
    const int wid  = threadIdx.x >> 6;
    const int lane = threadIdx.x & 63;
    const int row  = blockIdx.x * 4 + wid;
    const float4 v = ((const float4*)(feat + (size_t)row * DDIM))[lane];
    float ss = v.x * v.x + v.y * v.y + v.z * v.z + v.w * v.w;
    #pragma unroll
    for (int off = 32; off > 0; off >>= 1) ss += __shfl_xor(ss, off, 64);
    const float inv = rsqrtf(ss);
    ushort4 o;
    o.x = f32_to_bf16(v.x * inv);
    o.y = f32_to_bf16(v.y * inv);
    o.z = f32_to_bf16(v.z * inv);
    o.w = f32_to_bf16(v.w * inv);
    const int C    = lane >> 3;                       // k / 32 (k = lane*4)
    const int tile = C * 512 + (row >> 4);
    const int l16  = (row & 15) + (((lane >> 1) & 3) << 4);
    *(ushort4*)(anchorT + (size_t)tile * 512 + l16 * 8 + (lane & 1) * 4) = o;
}

// ---------------- fused sim-tile + full loss partials (upper triangle) ----------------
// part planes: part[q][Jt_slab][8192], q in {0:dsum,1:s1,2:w1,3:s2,4:cnt}
__global__ __launch_bounds__(256, 3) void simloss_kernel(
    const unsigned short* __restrict__ anchorT,
    const int* __restrict__ labels,
    float* __restrict__ part)
{
    __shared__ float rowPart[2][BM][5];
    __shared__ float colPart[2][BN][5];
    __shared__ int rowLab[BM];
    __shared__ int colLab[BN];

    // ---- supertile decode: 4x4 supergrid of 16x16-tile supertiles, upper tri ----
    // order: (0,0)d (0,1) (0,2) (0,3) (1,1)d (1,2) (1,3) (2,2)d (2,3) (3,3)d
    const int t = blockIdx.x;
    const int off1 = 136, off2 = 392, off3 = 648, off4 = 904, off5 = 1040,
              off6 = 1296, off7 = 1552, off8 = 1688, off9 = 1944;
    int b = (t >= off1) + (t >= off2) + (t >= off3) + (t >= off4) + (t >= off5)
          + (t >= off6) + (t >= off7) + (t >= off8) + (t >= off9);
    int si, sj, r0;
    switch (b) {
        case 0: si = 0; sj = 0; r0 = 0;    break;
        case 1: si = 0; sj = 1; r0 = off1; break;
        case 2: si = 0; sj = 2; r0 = off2; break;
        case 3: si = 0; sj = 3; r0 = off3; break;
        case 4: si = 1; sj = 1; r0 = off4; break;
        case 5: si = 1; sj = 2; r0 = off5; break;
        case 6: si = 1; sj = 3; r0 = off6; break;
        case 7: si = 2; sj = 2; r0 = off7; break;
        case 8: si = 2; sj = 3; r0 = off8; break;
        default: si = 3; sj = 3; r0 = off9; break;
    }
    const int rr = t - r0;
    int il, jl;
    if (si == sj) {   // triangular within 16x16
        il = 0;
        #pragma unroll
        for (int q = 1; q < 16; q++) if (rr >= (16 * q - (q * (q - 1)) / 2)) il = q;
        jl = il + (rr - (16 * il - (il * (il - 1)) / 2));
    } else {
        il = rr >> 4;
        jl = rr & 15;
    }
    const int It = si * 16 + il;
    const int Jt = sj * 16 + jl;
    const bool diag = (It == Jt);
    const int I0 = It * BM, J0 = Jt * BN;

    const int tid  = threadIdx.x;
    const int wid  = tid >> 6;
    const int lane = tid & 63;
    const int waveM = (wid >> 1) * 64;   // 2x2 wave grid over 128x128
    const int waveN = (wid & 1) * 64;
    const int cl = lane & 15;            // column within 16x16 frag
    const int rg = lane >> 4;            // row group (rows rg*4 + r)
    const bool dwave = diag && (waveM == waveN);

    if (tid < BM) rowLab[tid] = labels[I0 + tid];
    else          colLab[tid - BM] = labels[J0 + tid - BM];

    // per-lane fragment bases (1 KB coalesced load per fragment)
    const unsigned short* aBase = anchorT + (size_t)(It * 8 + (waveM >> 4)) * 512 + lane * 8;
    const unsigned short* bBase = anchorT + (size_t)(Jt * 8 + (waveN >> 4)) * 512 + lane * 8;

    f32x4 c_acc[4][4];
    #pragma unroll
    for (int a = 0; a < 4; a++)
        #pragma unroll
        for (int bq = 0; bq < 4; bq++)
            c_acc[a][bq] = (f32x4){0.f, 0.f, 0.f, 0.f};

    #pragma unroll
    for (int ks = 0; ks < 8; ks++) {
        const unsigned short* ap = aBase + (size_t)ks * (512 * 512);
        const unsigned short* bp = bBase + (size_t)ks * (512 * 512);
        // named scalars -> guaranteed register promotion (no scratch!)
        const bf16x8 a0 = *(const bf16x8*)(ap);
        const bf16x8 a1 = *(const bf16x8*)(ap + 512);
        const bf16x8 a2 = *(const bf16x8*)(ap + 1024);
        const bf16x8 a3 = *(const bf16x8*)(ap + 1536);
        const bf16x8 b0 = *(const bf16x8*)(bp);
        const bf16x8 b1 = *(const bf16x8*)(bp + 512);
        const bf16x8 b2 = *(const bf16x8*)(bp + 1024);
        const bf16x8 b3 = *(const bf16x8*)(bp + 1536);
        c_acc[0][0] = __builtin_amdgcn_mfma_f32_16x16x32_bf16(a0, b0, c_acc[0][0], 0, 0, 0);
        c_acc[0][1] = __builtin_amdgcn_mfma_f32_16x16x32_bf16(a0, b1, c_acc[0][1], 0, 0, 0);
        c_acc[0][2] = __builtin_amdgcn_mfma_f32_16x16x32_bf16(a0, b2, c_acc[0][2], 0, 0, 0);
        c_acc[0][3] = __builtin_amdgcn_mfma_f32_16x16x32_bf16(a0, b3, c_acc[0][3], 0, 0, 0);
        c_acc[1][0] = __builtin_amdgcn_mfma_f32_16x16x32_bf16(a1, b0, c_acc[1][0], 0, 0, 0);
        c_acc[1][1] = __builtin_amdgcn_mfma_f32_16x16x32_bf16(a1, b1, c_acc[1][1], 0, 0, 0);
        c_acc[1][2] = __builtin_amdgcn_mfma_f32_16x16x32_bf16(a1, b2, c_acc[1][2], 0, 0, 0);
        c_acc[1][3] = __builtin_amdgcn_mfma_f32_16x16x32_bf16(a1, b3, c_acc[1][3], 0, 0, 0);
        c_acc[2][0] = __builtin_amdgcn_mfma_f32_16x16x32_bf16(a2, b0, c_acc[2][0], 0, 0, 0);
        c_acc[2][1] = __builtin_amdgcn_mfma_f32_16x16x32_bf16(a2, b1, c_acc[2][1], 0, 0, 0);
        c_acc[2][2] = __builtin_amdgcn_mfma_f32_16x16x32_bf16(a2, b2, c_acc[2][2], 0, 0, 0);
        c_acc[2][3] = __builtin_amdgcn_mfma_f32_16x16x32_bf16(a2, b3, c_acc[2][3], 0, 0, 0);
        c_acc[3][0] = __builtin_amdgcn_mfma_f32_16x16x32_bf16(a3, b0, c_acc[3][0], 0, 0, 0);
        c_acc[3][1] = __builtin_amdgcn_mfma_f32_16x16x32_bf16(a3, b1, c_acc[3][1], 0, 0, 0);
        c_acc[3][2] = __builtin_amdgcn_mfma_f32_16x16x32_bf16(a3, b2, c_acc[3][2], 0, 0, 0);
        c_acc[3][3] = __builtin_amdgcn_mfma_f32_16x16x32_bf16(a3, b3, c_acc[3][3], 0, 0, 0);
    }
    __syncthreads();   // rowLab/colLab ready (placed late; labels load had 8 K-chunks to land)

    // ---- epilogue: weights/exp + masked sums, 5 quantities ----
    int ljr[4];
    #pragma unroll
    for (int fc = 0; fc < 4; fc++) ljr[fc] = colLab[waveN + fc * 16 + cl];

    float colA[5][4];
    #pragma unroll
    for (int q = 0; q < 5; q++)
        #pragma unroll
        for (int fc = 0; fc < 4; fc++) colA[q][fc] = 0.f;

    #pragma unroll
    for (int fr = 0; fr < 4; fr++) {
        float rA[5][4];
        #pragma unroll
        for (int q = 0; q < 5; q++)
            #pragma unroll
            for (int r = 0; r < 4; r++) rA[q][r] = 0.f;
        int li[4];
        #pragma unroll
        for (int r = 0; r < 4; r++) li[r] = rowLab[waveM + fr * 16 + rg * 4 + r];

        #pragma unroll
        for (int fc = 0; fc < 4; fc++) {
            const int lj = ljr[fc];
            const f32x4 c = c_acc[fr][fc];
            #pragma unroll
            for (int r = 0; r < 4; r++) {
                const float s = c[r];
                const bool self = diag && (fr == fc) && dwave && ((rg * 4 + r) == cl);
                float e = self ? 0.f : exp2f(fmaf(s, K_E1, K_E2));
                const float wn = fmaxf(fmaf(s, K_N1, K_N2), 1.0f);
                const float wp = fmaxf(1.5f - s, 1.0f);
                const float lp = fmaf(s, K_INVT, -K_INVT);
                const float mp = (!self && (li[r] == lj)) ? 1.f : 0.f;
                const float mpw = mp * wp;
                const float mne = (1.f - mp) * wn * e;   // self-safe: e==0
                rA[0][r] += e;
                rA[1][r] = fmaf(mpw, lp, rA[1][r]);
                rA[2][r] += mpw;
                rA[3][r] += mne;
                rA[4][r] += mp;
                if (!diag) {
                    colA[0][fc] += e;
                    colA[1][fc] = fmaf(mpw, lp, colA[1][fc]);
                    colA[2][fc] += mpw;
                    colA[3][fc] += mne;
                    colA[4][fc] += mp;
                }
            }
        }
        // reduce across 16 columns (lanes within rg group)
        #pragma unroll
        for (int q = 0; q < 5; q++)
            #pragma unroll
            for (int r = 0; r < 4; r++) {
                #pragma unroll
                for (int off = 1; off < 16; off <<= 1)
                    rA[q][r] += __shfl_xor(rA[q][r], off, 64);
            }
        if (cl == 0) {
            const int wh = waveN >> 6;
            #pragma unroll
            for (int r = 0; r < 4; r++) {
                const int row = waveM + fr * 16 + rg * 4 + r;
                #pragma unroll
                for (int q = 0; q < 5; q++) rowPart[wh][row][q] = rA[q][r];
            }
        }
    }
    if (!diag) {
        #pragma unroll
        for (int q = 0; q < 5; q++)
            #pragma unroll
            for (int fc = 0; fc < 4; fc++) {
                colA[q][fc] += __shfl_xor(colA[q][fc], 16, 64);
                colA[q][fc] += __shfl_xor(colA[q][fc], 32, 64);
            }
        if (rg == 0) {
            const int wmh = waveM >> 6;
            #pragma unroll
            for (int fc = 0; fc < 4; fc++) {
                const int col = waveN + fc * 16 + cl;
                #pragma unroll
                for (int q = 0; q < 5; q++) colPart[wmh][col][q] = colA[q][fc];
            }
        }
    }

    __syncthreads();
    if (tid < BM) {
        #pragma unroll
        for (int q = 0; q < 5; q++) {
            const float v = rowPart[0][tid][q] + rowPart[1][tid][q];
            part[((size_t)q * NT + Jt) * BSZ + I0 + tid] = v;
        }
    } else if (!diag) {
        const int c = tid - BM;
        #pragma unroll
        for (int q = 0; q < 5; q++) {
            const float v = colPart[0][c][q] + colPart[1][c][q];
            part[((size_t)q * NT + It) * BSZ + J0 + c] = v;
        }
    }
}

// ---------------- per-row combine + block partial sums ----------------
__global__ __launch_bounds__(256) void reduce_kernel(
    const float* __restrict__ part, double* __restrict__ partial)
{
    const int i = blockIdx.x * 256 + threadIdx.x;
    float dsum = 0.f, s1 = 0.f, w1 = 0.f, s2 = 0.f, cnt = 0.f;
    #pragma unroll 4
    for (int j = 0; j < NT; j++) {
        dsum += part[((size_t)0 * NT + j) * BSZ + i];
        s1   += part[((size_t)1 * NT + j) * BSZ + i];
        w1   += part[((size_t)2 * NT + j) * BSZ + i];
        s2   += part[((size_t)3 * NT + j) * BSZ + i];
        cnt  += part[((size_t)4 * NT + j) * BSZ + i];
    }
    const float pc = fmaxf(cnt, 1.0f);
    const float nc = fmaxf(8191.0f - cnt, 1.0f);
    const float ld = logf(dsum);
    const double pos_i = (double)((s1 - ld * w1) / pc);
    const double neg_i = (double)((s2 / dsum) / nc);

    __shared__ double sp[256], sn[256];
    sp[threadIdx.x] = pos_i; sn[threadIdx.x] = neg_i;
    __syncthreads();
    for (int s = 128; s > 0; s >>= 1) {
        if (threadIdx.x < s) {
            sp[threadIdx.x] += sp[threadIdx.x + s];
            sn[threadIdx.x] += sn[threadIdx.x + s];
        }
        __syncthreads();
    }
    if (threadIdx.x == 0) {
        partial[blockIdx.x * 2 + 0] = sp[0];
        partial[blockIdx.x * 2 + 1] = sn[0];
    }
}

// ---------------- final scalar ----------------
__global__ __launch_bounds__(64) void final_kernel(const double* __restrict__ partial,
                                                   float* __restrict__ out) {
    const int lane = threadIdx.x;
    double p = 0.0, n = 0.0;
    if (lane < 32) { p = partial[lane * 2 + 0]; n = partial[lane * 2 + 1]; }
    #pragma unroll
    for (int o = 32; o > 0; o >>= 1) { p += __shfl_xor(p, o, 64); n += __shfl_xor(n, o, 64); }
    if (lane == 0) out[0] = (float)(-p / (double)BSZ + 0.3 * (n / (double)BSZ));
}

extern "C" void kernel_launch(void* const* d_in, const int* in_sizes, int n_in,
                              void* d_out, int out_size, void* d_ws, size_t ws_size,
                              hipStream_t stream) {
    const float* feat = (const float*)d_in[0];
    const int* labels = (const int*)d_in[1];
    float* out = (float*)d_out;

    char* ws = (char*)d_ws;
    unsigned short* anchorT = (unsigned short*)ws;                       // 4 MB MFMA-native
    const size_t anchorBytes = (size_t)BSZ * DDIM * sizeof(unsigned short);
    float* part = (float*)(ws + anchorBytes);                            // 5*64*8192 f32 = 10.5 MB
    const size_t partBytes = (size_t)5 * NT * BSZ * sizeof(float);
    double* partial = (double*)(ws + anchorBytes + partBytes);           // 512 B

    norm_kernel<<<BSZ / 4, 256, 0, stream>>>(feat, anchorT);
    simloss_kernel<<<NTRI, 256, 0, stream>>>(anchorT, labels, part);
    reduce_kernel<<<BSZ / 256, 256, 0, stream>>>(part, partial);
    final_kernel<<<1, 64, 0, stream>>>(partial, out);
}

// Round 6
// 122.386 us; speedup vs baseline: 2.1880x; 2.1880x over previous
//
#include <hip/hip_runtime.h>

#define BSZ  8192
#define DDIM 256
#define BM 128
#define BN 128
#define NT   64                  // tiles per dimension
#define NTRI (NT * (NT + 1) / 2) // 2080 upper-triangle tiles

typedef float f32x4 __attribute__((ext_vector_type(4)));
typedef short bf16x8 __attribute__((ext_vector_type(8)));

__device__ __forceinline__ unsigned short f32_to_bf16(float f) {
    unsigned int u = __float_as_uint(f);
    u += 0x7fffu + ((u >> 16) & 1u);   // RNE
    return (unsigned short)(u >> 16);
}

// epilogue constants
#define K_E1   20.60992915555662f    // (1/T)*log2(e)
#define K_E2  -20.60992915555662f
#define K_INVT 14.285714285714286f   // 1/T
#define K_N1   1.4285714285714286f   // 1/(1-0.3)
#define K_N2   0.5714285714285714f   // 0.4/0.7

// ---------------- L2-normalize rows; emit MFMA-fragment-native layout; zero posAcc ----------------
// anchorT: tile T = C*512 + R (C=k/32, R=row/16) is 1 KB at T*512 shorts; within tile,
// lane l = (row%16) + 16*((k%32)/8) holds elems j=0..7 (k = C*32 + (l>>4)*8 + j).
__global__ __launch_bounds__(256) void norm_kernel(const float* __restrict__ feat,
                                                   unsigned short* __restrict__ anchorT,
                                                   float* __restrict__ posAcc) {
    if (blockIdx.x < 128) posAcc[blockIdx.x * 256 + threadIdx.x] = 0.0f;
    const int wid  = threadIdx.x >> 6;
    const int lane = threadIdx.x & 63;
    const int row  = blockIdx.x * 4 + wid;
    const float4 v = ((const float4*)(feat + (size_t)row * DDIM))[lane];
    float ss = v.x * v.x + v.y * v.y + v.z * v.z + v.w * v.w;
    #pragma unroll
    for (int off = 32; off > 0; off >>= 1) ss += __shfl_xor(ss, off, 64);
    const float inv = rsqrtf(ss);
    ushort4 o;
    o.x = f32_to_bf16(v.x * inv);
    o.y = f32_to_bf16(v.y * inv);
    o.z = f32_to_bf16(v.z * inv);
    o.w = f32_to_bf16(v.w * inv);
    const int C    = lane >> 3;                       // k/32 (k = lane*4)
    const int tile = C * 512 + (row >> 4);
    const int l16  = (row & 15) + (((lane >> 1) & 3) << 4);
    *(ushort4*)(anchorT + (size_t)tile * 512 + l16 * 8 + (lane & 1) * 4) = o;
}

// ---------------- async global -> LDS, 16B/lane ----------------
__device__ __forceinline__ void gload_lds16(const unsigned short* g, unsigned short* l) {
    __builtin_amdgcn_global_load_lds(
        (const __attribute__((address_space(1))) void*)g,
        (__attribute__((address_space(3))) void*)l, 16, 0, 0);
}

// ---------------- fused sim-tile + loss partials (upper triangle) ----------------
// part: float2 {dsum, T2} per (slab, row); rare positive terms -> global atomics posAcc.
__global__ __launch_bounds__(256) void simloss_kernel(
    const unsigned short* __restrict__ anchorT,
    const int* __restrict__ labels,
    float* __restrict__ part,          // float2 planes [NT][BSZ]
    float* __restrict__ posAcc)        // [BSZ][4] {s1, w1, s2corr, cnt}
{
    __shared__ __align__(16) unsigned short As[16 * 512];  // 16 KB (BM x 64k, frag order)
    __shared__ __align__(16) unsigned short Bs[16 * 512];  // 16 KB
    __shared__ float rowDT[2][BM][2];
    __shared__ float colDT[2][BN][2];
    __shared__ int rowLab[BM];
    __shared__ int colLab[BN];

    // ---- supertile decode: 4x4 supergrid of 16x16-tile supertiles, upper tri ----
    const int t = blockIdx.x;
    const int off1 = 136, off2 = 392, off3 = 648, off4 = 904, off5 = 1040,
              off6 = 1296, off7 = 1552, off8 = 1688, off9 = 1944;
    int b = (t >= off1) + (t >= off2) + (t >= off3) + (t >= off4) + (t >= off5)
          + (t >= off6) + (t >= off7) + (t >= off8) + (t >= off9);
    int si, sj, r0;
    switch (b) {
        case 0: si = 0; sj = 0; r0 = 0;    break;
        case 1: si = 0; sj = 1; r0 = off1; break;
        case 2: si = 0; sj = 2; r0 = off2; break;
        case 3: si = 0; sj = 3; r0 = off3; break;
        case 4: si = 1; sj = 1; r0 = off4; break;
        case 5: si = 1; sj = 2; r0 = off5; break;
        case 6: si = 1; sj = 3; r0 = off6; break;
        case 7: si = 2; sj = 2; r0 = off7; break;
        case 8: si = 2; sj = 3; r0 = off8; break;
        default: si = 3; sj = 3; r0 = off9; break;
    }
    const int rr = t - r0;
    int il, jl;
    if (si == sj) {
        il = 0;
        #pragma unroll
        for (int q = 1; q < 16; q++) if (rr >= (16 * q - (q * (q - 1)) / 2)) il = q;
        jl = il + (rr - (16 * il - (il * (il - 1)) / 2));
    } else {
        il = rr >> 4;
        jl = rr & 15;
    }
    const int It = si * 16 + il;
    const int Jt = sj * 16 + jl;
    const bool diag = (It == Jt);
    const int I0 = It * BM, J0 = Jt * BN;

    const int tid  = threadIdx.x;
    const int wid  = tid >> 6;
    const int lane = tid & 63;
    const int waveM = (wid >> 1) * 64;
    const int waveN = (wid & 1) * 64;
    const int wm4 = waveM >> 4;          // 0 or 4
    const int wn4 = waveN >> 4;
    const int cl = lane & 15;
    const int rg = lane >> 4;
    const bool dwave = diag && (waveM == waveN);

    if (tid < BM) rowLab[tid] = labels[I0 + tid];
    else          colLab[tid - BM] = labels[J0 + tid - BM];

    f32x4 c_acc[4][4];
    #pragma unroll
    for (int a = 0; a < 4; a++)
        #pragma unroll
        for (int bq = 0; bq < 4; bq++)
            c_acc[a][bq] = (f32x4){0.f, 0.f, 0.f, 0.f};

    const int laneOff = lane * 8;   // shorts (16 B per lane)

    for (int kc = 0; kc < 4; kc++) {          // BK = 64 (two 32-wide K-tiles)
        const int C0 = kc * 2;
        #pragma unroll
        for (int q = 0; q < 4; q++) {
            const int chunk = wid * 4 + q;    // 0..15
            const int cq = chunk >> 3;        // 0/1 (K-subtile)
            const int Rq = chunk & 7;         // row-tile within the 8
            const size_t at = ((size_t)(C0 + cq) * 512 + It * 8 + Rq) * 512;
            const size_t bt = ((size_t)(C0 + cq) * 512 + Jt * 8 + Rq) * 512;
            gload_lds16(anchorT + at + laneOff, &As[chunk * 512]);
            gload_lds16(anchorT + bt + laneOff, &Bs[chunk * 512]);
        }
        __syncthreads();
        #pragma unroll
        for (int ks = 0; ks < 2; ks++) {
            const unsigned short* ab = &As[(ks * 8 + wm4) * 512 + laneOff];
            const unsigned short* bb = &Bs[(ks * 8 + wn4) * 512 + laneOff];
            const bf16x8 a0 = *(const bf16x8*)(ab);
            const bf16x8 a1 = *(const bf16x8*)(ab + 512);
            const bf16x8 a2 = *(const bf16x8*)(ab + 1024);
            const bf16x8 a3 = *(const bf16x8*)(ab + 1536);
            const bf16x8 b0 = *(const bf16x8*)(bb);
            const bf16x8 b1 = *(const bf16x8*)(bb + 512);
            const bf16x8 b2 = *(const bf16x8*)(bb + 1024);
            const bf16x8 b3 = *(const bf16x8*)(bb + 1536);
            c_acc[0][0] = __builtin_amdgcn_mfma_f32_16x16x32_bf16(a0, b0, c_acc[0][0], 0, 0, 0);
            c_acc[0][1] = __builtin_amdgcn_mfma_f32_16x16x32_bf16(a0, b1, c_acc[0][1], 0, 0, 0);
            c_acc[0][2] = __builtin_amdgcn_mfma_f32_16x16x32_bf16(a0, b2, c_acc[0][2], 0, 0, 0);
            c_acc[0][3] = __builtin_amdgcn_mfma_f32_16x16x32_bf16(a0, b3, c_acc[0][3], 0, 0, 0);
            c_acc[1][0] = __builtin_amdgcn_mfma_f32_16x16x32_bf16(a1, b0, c_acc[1][0], 0, 0, 0);
            c_acc[1][1] = __builtin_amdgcn_mfma_f32_16x16x32_bf16(a1, b1, c_acc[1][1], 0, 0, 0);
            c_acc[1][2] = __builtin_amdgcn_mfma_f32_16x16x32_bf16(a1, b2, c_acc[1][2], 0, 0, 0);
            c_acc[1][3] = __builtin_amdgcn_mfma_f32_16x16x32_bf16(a1, b3, c_acc[1][3], 0, 0, 0);
            c_acc[2][0] = __builtin_amdgcn_mfma_f32_16x16x32_bf16(a2, b0, c_acc[2][0], 0, 0, 0);
            c_acc[2][1] = __builtin_amdgcn_mfma_f32_16x16x32_bf16(a2, b1, c_acc[2][1], 0, 0, 0);
            c_acc[2][2] = __builtin_amdgcn_mfma_f32_16x16x32_bf16(a2, b2, c_acc[2][2], 0, 0, 0);
            c_acc[2][3] = __builtin_amdgcn_mfma_f32_16x16x32_bf16(a2, b3, c_acc[2][3], 0, 0, 0);
            c_acc[3][0] = __builtin_amdgcn_mfma_f32_16x16x32_bf16(a3, b0, c_acc[3][0], 0, 0, 0);
            c_acc[3][1] = __builtin_amdgcn_mfma_f32_16x16x32_bf16(a3, b1, c_acc[3][1], 0, 0, 0);
            c_acc[3][2] = __builtin_amdgcn_mfma_f32_16x16x32_bf16(a3, b2, c_acc[3][2], 0, 0, 0);
            c_acc[3][3] = __builtin_amdgcn_mfma_f32_16x16x32_bf16(a3, b3, c_acc[3][3], 0, 0, 0);
        }
        __syncthreads();
    }

    // ---- epilogue: hot path = dsum/T2 only; positives are rare -> global atomics ----
    int ljr[4], gjr[4];
    #pragma unroll
    for (int fc = 0; fc < 4; fc++) {
        const int cidx = waveN + fc * 16 + cl;
        ljr[fc] = colLab[cidx];
        gjr[fc] = J0 + cidx;
    }
    float cd[4] = {0.f, 0.f, 0.f, 0.f}, ct[4] = {0.f, 0.f, 0.f, 0.f};

    #pragma unroll
    for (int fr = 0; fr < 4; fr++) {
        float rd[4] = {0.f, 0.f, 0.f, 0.f}, rt[4] = {0.f, 0.f, 0.f, 0.f};
        int li[4], gi[4];
        #pragma unroll
        for (int r = 0; r < 4; r++) {
            const int ridx = waveM + fr * 16 + rg * 4 + r;
            li[r] = rowLab[ridx];
            gi[r] = I0 + ridx;
        }
        #pragma unroll
        for (int fc = 0; fc < 4; fc++) {
            const int lj = ljr[fc];
            const f32x4 c = c_acc[fr][fc];
            #pragma unroll
            for (int r = 0; r < 4; r++) {
                const float s = c[r];
                const bool self = diag && (fr == fc) && dwave && ((rg * 4 + r) == cl);
                const float e  = self ? 0.f : exp2f(fmaf(s, K_E1, K_E2));
                const float wn = fmaxf(fmaf(s, K_N1, K_N2), 1.0f);
                const float we = wn * e;
                rd[r] += e;  rt[r] += we;
                if (!diag) { cd[fc] += e; ct[fc] += we; }
                if (li[r] == lj && !self) {   // rare (~0.1%)
                    const float wp = fmaxf(1.5f - s, 1.0f);
                    const float slp = fmaf(s, K_INVT, -K_INVT) * wp;   // wp*lp
                    float* pi = posAcc + (size_t)gi[r] * 4;
                    atomicAdd(pi + 0, slp);
                    atomicAdd(pi + 1, wp);
                    atomicAdd(pi + 2, we);
                    atomicAdd(pi + 3, 1.0f);
                    if (!diag) {
                        float* pj = posAcc + (size_t)gjr[fc] * 4;
                        atomicAdd(pj + 0, slp);
                        atomicAdd(pj + 1, wp);
                        atomicAdd(pj + 2, we);
                        atomicAdd(pj + 3, 1.0f);
                    }
                }
            }
        }
        #pragma unroll
        for (int r = 0; r < 4; r++) {
            #pragma unroll
            for (int off = 1; off < 16; off <<= 1) {
                rd[r] += __shfl_xor(rd[r], off, 64);
                rt[r] += __shfl_xor(rt[r], off, 64);
            }
        }
        if (cl == 0) {
            const int wh = waveN >> 6;
            #pragma unroll
            for (int r = 0; r < 4; r++) {
                const int row = waveM + fr * 16 + rg * 4 + r;
                rowDT[wh][row][0] = rd[r];
                rowDT[wh][row][1] = rt[r];
            }
        }
    }
    if (!diag) {
        #pragma unroll
        for (int fc = 0; fc < 4; fc++) {
            cd[fc] += __shfl_xor(cd[fc], 16, 64);
            cd[fc] += __shfl_xor(cd[fc], 32, 64);
            ct[fc] += __shfl_xor(ct[fc], 16, 64);
            ct[fc] += __shfl_xor(ct[fc], 32, 64);
        }
        if (rg == 0) {
            const int wmh = waveM >> 6;
            #pragma unroll
            for (int fc = 0; fc < 4; fc++) {
                const int col = waveN + fc * 16 + cl;
                colDT[wmh][col][0] = cd[fc];
                colDT[wmh][col][1] = ct[fc];
            }
        }
    }

    __syncthreads();
    if (tid < BM) {
        float2 v;
        v.x = rowDT[0][tid][0] + rowDT[1][tid][0];
        v.y = rowDT[0][tid][1] + rowDT[1][tid][1];
        ((float2*)part)[(size_t)Jt * BSZ + I0 + tid] = v;
    } else if (!diag) {
        const int c = tid - BM;
        float2 v;
        v.x = colDT[0][c][0] + colDT[1][c][0];
        v.y = colDT[0][c][1] + colDT[1][c][1];
        ((float2*)part)[(size_t)It * BSZ + J0 + c] = v;
    }
}

// ---------------- per-row combine + block partial sums ----------------
__global__ __launch_bounds__(256) void reduce_kernel(
    const float* __restrict__ part, const float* __restrict__ posAcc,
    double* __restrict__ partial)
{
    const int i = blockIdx.x * 256 + threadIdx.x;
    float dsum = 0.f, T2 = 0.f;
    const float2* p2 = (const float2*)part;
    #pragma unroll 8
    for (int j = 0; j < NT; j++) {
        const float2 v = p2[(size_t)j * BSZ + i];
        dsum += v.x; T2 += v.y;
    }
    const float4 pa = ((const float4*)posAcc)[i];   // {s1, w1, s2corr, cnt}
    const float s1 = pa.x, w1 = pa.y, s2 = T2 - pa.z, cnt = pa.w;
    const float pc = fmaxf(cnt, 1.0f);
    const float nc = fmaxf(8191.0f - cnt, 1.0f);
    const float ld = logf(dsum);
    const double pos_i = (double)((s1 - ld * w1) / pc);
    const double neg_i = (double)((s2 / dsum) / nc);

    __shared__ double sp[256], sn[256];
    sp[threadIdx.x] = pos_i; sn[threadIdx.x] = neg_i;
    __syncthreads();
    for (int s = 128; s > 0; s >>= 1) {
        if (threadIdx.x < s) {
            sp[threadIdx.x] += sp[threadIdx.x + s];
            sn[threadIdx.x] += sn[threadIdx.x + s];
        }
        __syncthreads();
    }
    if (threadIdx.x == 0) {
        partial[blockIdx.x * 2 + 0] = sp[0];
        partial[blockIdx.x * 2 + 1] = sn[0];
    }
}

// ---------------- final scalar ----------------
__global__ __launch_bounds__(64) void final_kernel(const double* __restrict__ partial,
                                                   float* __restrict__ out) {
    const int lane = threadIdx.x;
    double p = 0.0, n = 0.0;
    if (lane < 32) { p = partial[lane * 2 + 0]; n = partial[lane * 2 + 1]; }
    #pragma unroll
    for (int o = 32; o > 0; o >>= 1) { p += __shfl_xor(p, o, 64); n += __shfl_xor(n, o, 64); }
    if (lane == 0) out[0] = (float)(-p / (double)BSZ + 0.3 * (n / (double)BSZ));
}

extern "C" void kernel_launch(void* const* d_in, const int* in_sizes, int n_in,
                              void* d_out, int out_size, void* d_ws, size_t ws_size,
                              hipStream_t stream) {
    const float* feat = (const float*)d_in[0];
    const int* labels = (const int*)d_in[1];
    float* out = (float*)d_out;

    char* ws = (char*)d_ws;
    unsigned short* anchorT = (unsigned short*)ws;                       // 4 MB MFMA-native
    const size_t anchorBytes = (size_t)BSZ * DDIM * sizeof(unsigned short);
    float* part = (float*)(ws + anchorBytes);                            // 64*8192 float2 = 4 MB
    const size_t partBytes = (size_t)NT * BSZ * 2 * sizeof(float);
    float* posAcc = (float*)(ws + anchorBytes + partBytes);              // 128 KB
    const size_t posBytes = (size_t)BSZ * 4 * sizeof(float);
    double* partial = (double*)(ws + anchorBytes + partBytes + posBytes); // 512 B

    norm_kernel<<<BSZ / 4, 256, 0, stream>>>(feat, anchorT, posAcc);
    simloss_kernel<<<NTRI, 256, 0, stream>>>(anchorT, labels, part, posAcc);
    reduce_kernel<<<BSZ / 256, 256, 0, stream>>>(part, posAcc, partial);
    final_kernel<<<1, 64, 0, stream>>>(partial, out);
}